// Round 15
// baseline (328.347 us; speedup 1.0000x reference)
//
#include <hip/hip_runtime.h>
#include <cstddef>

// SSA forward, round 15:
//  - gemm8 BK=256 (64KB LDS): occupancy already register-capped at 2 blocks/CU
//    with 32KB, and 160/64=2 -> no occupancy loss, but barrier-drain events
//    halve (conv/attn/proj 4->2 iters, kv 8->4) — targets the observed stall
//    (MfmaUtil 14%, VALU 15%, HBM 12%: nothing busy, drain-bound short K-loop).
//  - dispatch fusion: transpose+wcvt -> prep_k; apply_qT+apply_kv -> apply_all_k
//    (13 -> 11 dispatches); qT tile load vectorized to uchar4.
//  - numerics identical to round 14 (same MFMA order/encoders) -> absmax 0.0.

#define CC 512
#define BB 32
#define NN 1024

typedef __attribute__((ext_vector_type(4))) float v4f;
typedef __attribute__((ext_vector_type(2))) float v2f;
typedef __attribute__((ext_vector_type(4))) int v4i;
typedef __attribute__((ext_vector_type(8))) int v8i;
typedef unsigned char uchar;
typedef unsigned long long ull;

// ---- soft fallbacks --------------------------------------------------------------
__device__ __forceinline__ uchar f2e4s(float v) {
  const uchar s = (v < 0.f) ? 0x80 : 0x00;
  float a = fabsf(v);
  if (a >= 464.f) return s | 0x7E;
  if (a < 0.015625f) {
    int q = (int)rintf(a * 512.f);
    return s | (uchar)q;
  }
  const int e = (int)((__float_as_uint(a) >> 23) & 0xFF) - 126;
  const float scale = __uint_as_float((unsigned)(4 - e + 127) << 23);
  const int q = (int)rintf(a * scale);
  int code = ((e - 1 + 7) << 3) + (q - 8);
  if (code > 0x7E) code = 0x7E;
  return s | (uchar)code;
}
__device__ __forceinline__ float e42f(uchar b) {
  const int e = (b >> 3) & 15, m = b & 7;
  const float mag = e ? __uint_as_float((unsigned)((e + 120) << 23) | ((unsigned)m << 20))
                      : (float)m * 0.001953125f;
  return (b & 0x80) ? -mag : mag;
}

// ---- HW converters (gfx950 OCP e4m3), guarded ------------------------------------
__device__ __forceinline__ unsigned pk4_fp8(float a0, float a1, float a2, float a3) {
#if __has_builtin(__builtin_amdgcn_cvt_pk_fp8_f32)
  int r = __builtin_amdgcn_cvt_pk_fp8_f32(a0, a1, 0, false);
  r = __builtin_amdgcn_cvt_pk_fp8_f32(a2, a3, r, true);
  return (unsigned)r;
#else
  return (unsigned)f2e4s(a0) | ((unsigned)f2e4s(a1) << 8) |
         ((unsigned)f2e4s(a2) << 16) | ((unsigned)f2e4s(a3) << 24);
#endif
}
__device__ __forceinline__ uchar enc1(float v) {
#if __has_builtin(__builtin_amdgcn_cvt_pk_fp8_f32)
  return (uchar)(__builtin_amdgcn_cvt_pk_fp8_f32(v, v, 0, false) & 0xFF);
#else
  return f2e4s(v);
#endif
}
template <bool HI>
__device__ __forceinline__ v2f dec2(int src) {
#if __has_builtin(__builtin_amdgcn_cvt_pk_f32_fp8)
  return __builtin_amdgcn_cvt_pk_f32_fp8(src, HI);
#else
  v2f r;
  const int s = HI ? (src >> 16) : src;
  r[0] = e42f((uchar)s);
  r[1] = e42f((uchar)(s >> 8));
  return r;
#endif
}

__device__ __forceinline__ void gload16(const void* g, void* l) {
  __builtin_amdgcn_global_load_lds(
      (const __attribute__((address_space(1))) unsigned int*)g,
      (__attribute__((address_space(3))) unsigned int*)l, 16, 0, 0);
}

// ---------------- batched NT GEMM, MX fp8, 128x128 tile, BK=256 ------------------
// LDS: A [0,32768) = 2 groups x 8 chunks x 2048B; B [32768,65536). Group g covers
// k = k0 + 128g + [0,128); within a group the layout is the round-14-proven one.
// EPI: 0 = fp8 (kv ints); 1 = attn spike {0,0x38}; 2 = fp8 pre-act;
//      3 = +bias[row] then fp8 pre-act.
template <int EPI>
__global__ __launch_bounds__(256) void gemm8(const uchar* __restrict__ A,
                                             const uchar* __restrict__ B,
                                             uchar* __restrict__ Cout,
                                             const float* __restrict__ bias,
                                             int M, int N, int K,
                                             long sA, long sB, long sC) {
  __shared__ __align__(16) uchar lds[65536];
  const int b = blockIdx.z;
  const uchar* Ab = A + (size_t)b * sA;
  const uchar* Bb = B + (size_t)b * sB;
  const int m0 = blockIdx.y * 128, n0 = blockIdx.x * 128;
  const int tid = threadIdx.x;
  const int wave = tid >> 6, lane = tid & 63;
  const int lrow = lane & 15, lquad = lane >> 4;
  const int wr = wave >> 1, wc = wave & 1;

  v4f acc[4][4];
#pragma unroll
  for (int i = 0; i < 4; i++)
#pragma unroll
    for (int j = 0; j < 4; j++) acc[i][j] = (v4f)0.f;

  const uchar* gA0 = Ab + (size_t)(m0 + 32 * wave + lrow) * K + lquad * 32;
  const uchar* gA1 = gA0 + (size_t)16 * K;
  const uchar* gB0 = Bb + (size_t)(n0 + 32 * wave + lrow) * K + lquad * 32;
  const uchar* gB1 = gB0 + (size_t)16 * K;
  uchar* lA0 = lds + (2 * wave) * 2048;          // group0, chunk 2w
  uchar* lA1 = lA0 + 2048;                       // group0, chunk 2w+1
  uchar* lB0 = lds + 32768 + (2 * wave) * 2048;
  uchar* lB1 = lB0 + 2048;

  for (int k0 = 0; k0 < K; k0 += 256) {
#pragma unroll
    for (int g = 0; g < 2; g++) {
      const int go = g * 128;     // global k offset of group g
      const int lo = g * 16384;   // LDS offset of group g
      gload16(gA0 + go,      lA0 + lo);
      gload16(gA0 + go + 16, lA0 + lo + 1024);
      gload16(gA1 + go,      lA1 + lo);
      gload16(gA1 + go + 16, lA1 + lo + 1024);
      gload16(gB0 + go,      lB0 + lo);
      gload16(gB0 + go + 16, lB0 + lo + 1024);
      gload16(gB1 + go,      lB1 + lo);
      gload16(gB1 + go + 16, lB1 + lo + 1024);
    }
    gA0 += 256; gA1 += 256; gB0 += 256; gB1 += 256;
    __syncthreads();
#pragma unroll
    for (int g = 0; g < 2; g++) {
      const uchar* ra = lds + g * 16384 + (size_t)(4 * wr) * 2048 + 16 * lane;
      const uchar* rb = lds + 32768 + g * 16384 + (size_t)(4 * wc) * 2048 + 16 * lane;
      v8i af[4], bf[4];
#pragma unroll
      for (int i = 0; i < 4; i++) {
        const v4i lo4 = *(const v4i*)(ra + i * 2048);
        const v4i hi4 = *(const v4i*)(ra + i * 2048 + 1024);
        af[i][0] = lo4[0]; af[i][1] = lo4[1]; af[i][2] = lo4[2]; af[i][3] = lo4[3];
        af[i][4] = hi4[0]; af[i][5] = hi4[1]; af[i][6] = hi4[2]; af[i][7] = hi4[3];
      }
#pragma unroll
      for (int j = 0; j < 4; j++) {
        const v4i lo4 = *(const v4i*)(rb + j * 2048);
        const v4i hi4 = *(const v4i*)(rb + j * 2048 + 1024);
        bf[j][0] = lo4[0]; bf[j][1] = lo4[1]; bf[j][2] = lo4[2]; bf[j][3] = lo4[3];
        bf[j][4] = hi4[0]; bf[j][5] = hi4[1]; bf[j][6] = hi4[2]; bf[j][7] = hi4[3];
      }
#pragma unroll
      for (int i = 0; i < 4; i++)
#pragma unroll
        for (int j = 0; j < 4; j++)
          acc[i][j] = __builtin_amdgcn_mfma_scale_f32_16x16x128_f8f6f4(
              af[i], bf[j], acc[i][j], 0, 0, 0, 127, 0, 127);
    }
    __syncthreads();
  }

  if (EPI == 3) {
#pragma unroll
    for (int mi = 0; mi < 4; mi++)
#pragma unroll
      for (int r = 0; r < 4; r++) {
        const float bi = bias[m0 + 64 * wr + 16 * mi + lquad * 4 + r];
#pragma unroll
        for (int ni = 0; ni < 4; ni++) acc[mi][ni][r] += bi;
      }
  }

  // Epilogue. C/D layout: col = lane&15, row = lquad*4 + reg.
#pragma unroll
  for (int mi = 0; mi < 4; mi++) {
    const int row0 = m0 + 64 * wr + 16 * mi + lquad * 4;
#pragma unroll
    for (int ni = 0; ni < 4; ni++) {
      const int col = n0 + 64 * wc + 16 * ni + lrow;
      uchar* cp = Cout + (size_t)b * sC + (size_t)row0 * N + col;
      if (EPI == 1) {
#pragma unroll
        for (int r = 0; r < 4; r++) {
          const float u = (acc[mi][ni][r] * 0.125f) / 1.1f - 0.5f;
          cp[(size_t)r * N] = (u >= 0.f) ? (uchar)0x38 : (uchar)0;
        }
      } else {
        const unsigned pk = pk4_fp8(acc[mi][ni][0], acc[mi][ni][1],
                                    acc[mi][ni][2], acc[mi][ni][3]);
#pragma unroll
        for (int r = 0; r < 4; r++) cp[(size_t)r * N] = (uchar)(pk >> (8 * r));
      }
    }
  }
}

// -------- BN partial stats from stored fp8: grid (8, nch) -------------------------
__global__ __launch_bounds__(256) void stats_part8_k(const uchar* __restrict__ in,
                                                     float* __restrict__ P,
                                                     long bstride) {
  const int part = blockIdx.x, c = blockIdx.y;
  const int tid = threadIdx.x;
  const int bi = part * 4 + (tid >> 6);
  const int lane = tid & 63;
  const uchar* p = in + (size_t)bi * bstride + (size_t)c * 1024 + lane * 16;
  const uint4 u = *(const uint4*)p;
  const int w4[4] = {(int)u.x, (int)u.y, (int)u.z, (int)u.w};
  float s = 0.f, s2 = 0.f;
#pragma unroll
  for (int t = 0; t < 4; t++) {
    const v2f a = dec2<false>(w4[t]);
    const v2f bb = dec2<true>(w4[t]);
    s += (a[0] + a[1]) + (bb[0] + bb[1]);
    s2 += a[0] * a[0] + a[1] * a[1] + bb[0] * bb[0] + bb[1] * bb[1];
  }
#pragma unroll
  for (int off = 32; off > 0; off >>= 1) {
    s += __shfl_down(s, off, 64);
    s2 += __shfl_down(s2, off, 64);
  }
  __shared__ float rs[4], rq[4];
  const int w = tid >> 6;
  if (lane == 0) { rs[w] = s; rq[w] = s2; }
  __syncthreads();
  if (tid == 0) {
    float2 o = make_float2(rs[0] + rs[1] + rs[2] + rs[3],
                           rq[0] + rq[1] + rq[2] + rq[3]);
    *(float2*)(P + (size_t)(c * 8 + part) * 2) = o;
  }
}

// -------- finalize: P[c][8][2] -> F[c] = (a,b), spike <=> a*x+b >= 1.1 ------------
__global__ __launch_bounds__(256) void finalize8_k(const float* __restrict__ P,
                                                   float2* __restrict__ F,
                                                   const float* __restrict__ g0, const float* __restrict__ b0,
                                                   const float* __restrict__ g1, const float* __restrict__ b1,
                                                   const float* __restrict__ g2, const float* __restrict__ b2,
                                                   int nch) {
  const int c = blockIdx.x * 256 + threadIdx.x;
  if (c >= nch) return;
  const float* pc = P + (size_t)c * 16;
  float S = 0.f, Q = 0.f;
#pragma unroll
  for (int t = 0; t < 8; t++) { S += pc[2 * t]; Q += pc[2 * t + 1]; }
  const float mean = S * (1.f / 32768.f);
  const float var = fmaxf(Q * (1.f / 32768.f) - mean * mean, 0.f);
  const float rinv = 1.f / sqrtf(var + 1e-5f);
  const int sec = c >> 9, cl = c & 511;
  const float g = (sec == 0 ? g0 : sec == 1 ? g1 : g2)[cl];
  const float bt = (sec == 0 ? b0 : sec == 1 ? b1 : b2)[cl];
  const float a = g * rinv;
  F[c] = make_float2(a, bt - mean * a);
}

// -------- fused BN-apply + spike: q (transpose) and k/v, one dispatch -------------
// blocks [0,16384): qT tiles; [16384,32768): k/v linear (8192 each).
__global__ __launch_bounds__(256) void apply_all_k(const uchar* __restrict__ qkv8,
                                                   uchar* __restrict__ q8,
                                                   uchar* __restrict__ k8,
                                                   uchar* __restrict__ v8,
                                                   const float2* __restrict__ F) {
  const int bid = blockIdx.x;
  const int tid = threadIdx.x;
  if (bid < 16384) {
    // q: BN-apply + spike + transpose -> q8 [B,N,C]
    __shared__ uchar tile[32][33];
    const int nb = bid & 31, cb = (bid >> 5) & 15, b = bid >> 9;
    const int n0 = nb * 32, c0 = cb * 32;
    const uchar* in = qkv8 + (size_t)b * (1536 * 1024);
    const int cl = tid >> 3;            // 0..31
    const int n4 = (tid & 7) * 4;       // 0..28
    const float2 ab = F[c0 + cl];
    const unsigned w = *(const unsigned*)(in + (size_t)(c0 + cl) * 1024 + n0 + n4);
    const v2f a = dec2<false>((int)w);
    const v2f bb = dec2<true>((int)w);
    tile[cl][n4 + 0] = (ab.x * a[0] + ab.y >= 1.1f) ? (uchar)0x38 : (uchar)0;
    tile[cl][n4 + 1] = (ab.x * a[1] + ab.y >= 1.1f) ? (uchar)0x38 : (uchar)0;
    tile[cl][n4 + 2] = (ab.x * bb[0] + ab.y >= 1.1f) ? (uchar)0x38 : (uchar)0;
    tile[cl][n4 + 3] = (ab.x * bb[1] + ab.y >= 1.1f) ? (uchar)0x38 : (uchar)0;
    __syncthreads();
    uchar* out = q8 + (size_t)b * (NN * CC);
    const int nl = tid >> 3;
    const int cq = (tid & 7) * 4;
    uchar4 v;
    v.x = tile[cq][nl]; v.y = tile[cq + 1][nl];
    v.z = tile[cq + 2][nl]; v.w = tile[cq + 3][nl];
    *(uchar4*)(out + (size_t)(n0 + nl) * CC + c0 + cq) = v;
  } else {
    // k/v: BN-apply + spike in [B,C,N]
    const int t0 = bid - 16384;
    const int sec = t0 >> 13;           // 0:k, 1:v
    const int blk = t0 & 8191;
    const size_t t = (size_t)blk * 256 + tid;
    const size_t i = t * 8;
    const int b = (int)(i >> 19);
    const int rem = (int)(i & 524287);
    const int c = rem >> 10, n = rem & 1023;
    const float2 ab = F[512 + 512 * sec + c];
    const uchar* src = qkv8 + (size_t)b * (1536 * 1024) + (size_t)(512 + 512 * sec + c) * 1024 + n;
    const uint2 u = *(const uint2*)src;
    ull packed = 0;
    {
      const v2f a = dec2<false>((int)u.x);
      const v2f bb = dec2<true>((int)u.x);
      const float f[4] = {a[0], a[1], bb[0], bb[1]};
#pragma unroll
      for (int j = 0; j < 4; j++)
        packed |= ((ab.x * f[j] + ab.y >= 1.1f) ? 0x38ull : 0ull) << (8 * j);
    }
    {
      const v2f a = dec2<false>((int)u.y);
      const v2f bb = dec2<true>((int)u.y);
      const float f[4] = {a[0], a[1], bb[0], bb[1]};
#pragma unroll
      for (int j = 0; j < 4; j++)
        packed |= ((ab.x * f[j] + ab.y >= 1.1f) ? 0x38ull : 0ull) << (8 * (4 + j));
    }
    uchar* dst = (sec ? v8 : k8) + (size_t)b * (CC * NN) + (size_t)c * 1024 + n;
    *(ull*)dst = packed;
  }
}

// -------- final BN apply + spike -> fp32 output -----------------------------------
__global__ __launch_bounds__(256) void apply_final_k(const uchar* __restrict__ in,
                                                     float* __restrict__ outp,
                                                     const float2* __restrict__ F) {
  const size_t idx = ((size_t)blockIdx.x * 256 + threadIdx.x) * 8;
  const int c = (int)((idx >> 10) & (CC - 1));
  const float2 ab = F[c];
  const uint2 u = *(const uint2*)(in + idx);
  float of[8];
  {
    const v2f a = dec2<false>((int)u.x);
    const v2f bb = dec2<true>((int)u.x);
    of[0] = (ab.x * a[0] + ab.y >= 1.1f) ? 1.f : 0.f;
    of[1] = (ab.x * a[1] + ab.y >= 1.1f) ? 1.f : 0.f;
    of[2] = (ab.x * bb[0] + ab.y >= 1.1f) ? 1.f : 0.f;
    of[3] = (ab.x * bb[1] + ab.y >= 1.1f) ? 1.f : 0.f;
  }
  {
    const v2f a = dec2<false>((int)u.y);
    const v2f bb = dec2<true>((int)u.y);
    of[4] = (ab.x * a[0] + ab.y >= 1.1f) ? 1.f : 0.f;
    of[5] = (ab.x * a[1] + ab.y >= 1.1f) ? 1.f : 0.f;
    of[6] = (ab.x * bb[0] + ab.y >= 1.1f) ? 1.f : 0.f;
    of[7] = (ab.x * bb[1] + ab.y >= 1.1f) ? 1.f : 0.f;
  }
  float* op = outp + idx;
  *(float4*)op = make_float4(of[0], of[1], of[2], of[3]);
  *(float4*)(op + 4) = make_float4(of[4], of[5], of[6], of[7]);
}

// -------- fused prep: x transpose->fp8 [blocks 0,16384) + weight cvt [16384,17408)
__global__ __launch_bounds__(256) void prep_k(const float* __restrict__ x,
                                              const float* __restrict__ w0, const float* __restrict__ w1,
                                              const float* __restrict__ w2, const float* __restrict__ w3,
                                              uchar* __restrict__ xT8,
                                              uchar* __restrict__ o0, uchar* __restrict__ o1,
                                              uchar* __restrict__ o2, uchar* __restrict__ o3) {
  const int bid = blockIdx.x;
  const int tid = threadIdx.x;
  if (bid < 16384) {
    __shared__ uchar tile[32][33];
    const int nb = bid & 31, cb = (bid >> 5) & 15, b = bid >> 9;
    const int n0 = nb * 32, c0 = cb * 32;
    const float* in = x + (size_t)b * (CC * NN);
    const int tx = tid & 31, ty = tid >> 5;
#pragma unroll
    for (int i = 0; i < 32; i += 8) {
      tile[ty + i][tx] = enc1(in[(size_t)(c0 + ty + i) * NN + n0 + tx]);
    }
    __syncthreads();
    uchar* o = xT8 + (size_t)b * (NN * CC);
    const int nl = tid >> 3;
    const int cq = (tid & 7) * 4;
    uchar4 v;
    v.x = tile[cq][nl]; v.y = tile[cq + 1][nl];
    v.z = tile[cq + 2][nl]; v.w = tile[cq + 3][nl];
    *(uchar4*)(o + (size_t)(n0 + nl) * CC + c0 + cq) = v;
  } else {
    const int t = bid - 16384;      // [0,1024)
    const int mat = t >> 8, blk = t & 255;
    const float* src = (mat == 0) ? w0 : (mat == 1) ? w1 : (mat == 2) ? w2 : w3;
    uchar* dst = (mat == 0) ? o0 : (mat == 1) ? o1 : (mat == 2) ? o2 : o3;
    const int i = (blk * 256 + tid) * 4;
    float4 v = *(const float4*)(src + i);
    *(unsigned*)(dst + i) = pk4_fp8(v.x, v.y, v.z, v.w);
  }
}

extern "C" void kernel_launch(void* const* d_in, const int* in_sizes, int n_in,
                              void* d_out, int out_size, void* d_ws, size_t ws_size,
                              hipStream_t stream) {
  const float* x          = (const float*)d_in[0];
  const float* q_w        = (const float*)d_in[1];
  const float* q_gamma    = (const float*)d_in[2];
  const float* q_beta     = (const float*)d_in[3];
  const float* k_w        = (const float*)d_in[4];
  const float* k_gamma    = (const float*)d_in[5];
  const float* k_beta     = (const float*)d_in[6];
  const float* v_w        = (const float*)d_in[7];
  const float* v_gamma    = (const float*)d_in[8];
  const float* v_beta     = (const float*)d_in[9];
  const float* proj_w     = (const float*)d_in[10];
  const float* proj_gamma = (const float*)d_in[11];
  const float* proj_beta  = (const float*)d_in[12];
  const float* proj_b     = (const float*)d_in[13];

  char* base = (char*)d_ws;
  const size_t MB = 1u << 20;
  uchar*  xT8    = (uchar*)base;                // 16 MB [B,N,C] fp8
  uchar*  qkv8   = (uchar*)(base + 16 * MB);    // 48 MB [B,1536,1024] fp8 pre-acts
  uchar*  q8     = (uchar*)(base + 64 * MB);    // 16 MB [B,N,C] fp8 spikes
  uchar*  k8     = (uchar*)(base + 80 * MB);    // 16 MB [B,C,N]
  uchar*  v8     = (uchar*)(base + 96 * MB);    // 16 MB [B,C,N]
  uchar*  kvT8   = (uchar*)(base + 112 * MB);   //  8 MB [B,d,c]
  uchar*  attnT8 = (uchar*)(base + 120 * MB);   // 16 MB [B,N,d]
  uchar*  outpre8= (uchar*)(base + 136 * MB);   // 16 MB [B,C,N] fp8 proj pre-acts
  uchar*  wqkv8  = (uchar*)(base + 152 * MB);   // stacked q|k|v fp8
  uchar*  wp8    = wqkv8 + 3 * CC * CC;
  float*  P      = (float*)(base + 154 * MB);   // conv partials [1536][8][2]
  float*  Pp     = P + 1536 * 16;               // proj partials [512][8][2]
  float2* F      = (float2*)(Pp + 512 * 16);
  float* dout = (float*)d_out;

  const long QKVL = (long)3 * CC * NN;   // fp8 bytes per batch
  const long NCL  = (long)NN * CC;
  const long CNL  = (long)CC * NN;
  const long KVL  = (long)CC * CC;

  // fused prep: x -> xT8 fp8 + weights -> fp8
  prep_k<<<17408, 256, 0, stream>>>(x, q_w, k_w, v_w, proj_w, xT8,
                                    wqkv8, wqkv8 + CC * CC, wqkv8 + 2 * CC * CC, wp8);

  // merged q/k/v conv -> fp8 pre-acts (K=512 -> 2 iters at BK=256)
  gemm8<2><<<dim3(NN / 128, 1536 / 128, BB), 256, 0, stream>>>(
      wqkv8, xT8, qkv8, nullptr, 1536, NN, CC, 0, NCL, QKVL);

  // BN stats from stored fp8, fold to affine
  stats_part8_k<<<dim3(8, 1536), 256, 0, stream>>>(qkv8, P, QKVL);
  finalize8_k<<<6, 256, 0, stream>>>(P, F, q_gamma, q_beta, k_gamma, k_beta,
                                     v_gamma, v_beta, 1536);

  // fused apply: q (transpose) + k + v spikes, one dispatch
  apply_all_k<<<32768, 256, 0, stream>>>(qkv8, q8, k8, v8, F);

  // kvT8[d][c] = sum_n v[d][n] k[c][n]   (K=1024 -> 4 iters)
  gemm8<0><<<dim3(CC / 128, CC / 128, BB), 256, 0, stream>>>(
      v8, k8, kvT8, nullptr, CC, CC, NN, CNL, CNL, KVL);
  // attnT8[n][d] = spike( sum_c q8[n][c]*kvT8[d][c] * 0.125, vth=0.5 )
  gemm8<1><<<dim3(CC / 128, NN / 128, BB), 256, 0, stream>>>(
      q8, kvT8, attnT8, nullptr, NN, CC, CC, NCL, KVL, NCL);
  // proj -> fp8 pre-acts (+bias)
  gemm8<3><<<dim3(NN / 128, CC / 128, BB), 256, 0, stream>>>(
      wp8, attnT8, outpre8, proj_b, CC, NN, CC, 0, NCL, CNL);

  // final BN (degenerate-safe: stats from stored fp8) + spike -> fp32 out
  stats_part8_k<<<dim3(8, CC), 256, 0, stream>>>(outpre8, Pp, CNL);
  finalize8_k<<<2, 256, 0, stream>>>(Pp, F, proj_gamma, proj_beta, proj_gamma,
                                     proj_beta, proj_gamma, proj_beta, CC);
  apply_final_k<<<8192, 256, 0, stream>>>(outpre8, dout, F);
}

// Round 16
// 325.475 us; speedup vs baseline: 1.0088x; 1.0088x over previous
//
#include <hip/hip_runtime.h>
#include <cstddef>

// SSA forward, round 16:
//  - REVERT gemm8 to BK=128 (round-14 proven: 72 VGPR, 25% occupancy; BK=256
//    was neutral-negative — 4th confirmation of the m97-structure plateau law).
//  - finalize folded into apply kernels (each thread reduces its channel's 8
//    partials in the SAME fp order as finalize8_k -> bit-identical affine,
//    degenerate-BN var=0 exactness preserved). Dispatches 11 -> 9.

#define CC 512
#define BB 32
#define NN 1024

typedef __attribute__((ext_vector_type(4))) float v4f;
typedef __attribute__((ext_vector_type(2))) float v2f;
typedef __attribute__((ext_vector_type(4))) int v4i;
typedef __attribute__((ext_vector_type(8))) int v8i;
typedef unsigned char uchar;
typedef unsigned long long ull;

// ---- soft fallbacks --------------------------------------------------------------
__device__ __forceinline__ uchar f2e4s(float v) {
  const uchar s = (v < 0.f) ? 0x80 : 0x00;
  float a = fabsf(v);
  if (a >= 464.f) return s | 0x7E;
  if (a < 0.015625f) {
    int q = (int)rintf(a * 512.f);
    return s | (uchar)q;
  }
  const int e = (int)((__float_as_uint(a) >> 23) & 0xFF) - 126;
  const float scale = __uint_as_float((unsigned)(4 - e + 127) << 23);
  const int q = (int)rintf(a * scale);
  int code = ((e - 1 + 7) << 3) + (q - 8);
  if (code > 0x7E) code = 0x7E;
  return s | (uchar)code;
}
__device__ __forceinline__ float e42f(uchar b) {
  const int e = (b >> 3) & 15, m = b & 7;
  const float mag = e ? __uint_as_float((unsigned)((e + 120) << 23) | ((unsigned)m << 20))
                      : (float)m * 0.001953125f;
  return (b & 0x80) ? -mag : mag;
}

// ---- HW converters (gfx950 OCP e4m3), guarded ------------------------------------
__device__ __forceinline__ unsigned pk4_fp8(float a0, float a1, float a2, float a3) {
#if __has_builtin(__builtin_amdgcn_cvt_pk_fp8_f32)
  int r = __builtin_amdgcn_cvt_pk_fp8_f32(a0, a1, 0, false);
  r = __builtin_amdgcn_cvt_pk_fp8_f32(a2, a3, r, true);
  return (unsigned)r;
#else
  return (unsigned)f2e4s(a0) | ((unsigned)f2e4s(a1) << 8) |
         ((unsigned)f2e4s(a2) << 16) | ((unsigned)f2e4s(a3) << 24);
#endif
}
__device__ __forceinline__ uchar enc1(float v) {
#if __has_builtin(__builtin_amdgcn_cvt_pk_fp8_f32)
  return (uchar)(__builtin_amdgcn_cvt_pk_fp8_f32(v, v, 0, false) & 0xFF);
#else
  return f2e4s(v);
#endif
}
template <bool HI>
__device__ __forceinline__ v2f dec2(int src) {
#if __has_builtin(__builtin_amdgcn_cvt_pk_f32_fp8)
  return __builtin_amdgcn_cvt_pk_f32_fp8(src, HI);
#else
  v2f r;
  const int s = HI ? (src >> 16) : src;
  r[0] = e42f((uchar)s);
  r[1] = e42f((uchar)(s >> 8));
  return r;
#endif
}

__device__ __forceinline__ void gload16(const void* g, void* l) {
  __builtin_amdgcn_global_load_lds(
      (const __attribute__((address_space(1))) unsigned int*)g,
      (__attribute__((address_space(3))) unsigned int*)l, 16, 0, 0);
}

// ---- channel affine from 8 partials (same fp order as the old finalize) ----------
__device__ __forceinline__ float2 chan_affine(const float* __restrict__ P, int c,
                                              float g, float bt) {
  const float* pc = P + (size_t)c * 16;
  float S = 0.f, Q = 0.f;
#pragma unroll
  for (int t = 0; t < 8; t++) { S += pc[2 * t]; Q += pc[2 * t + 1]; }
  const float mean = S * (1.f / 32768.f);
  const float var = fmaxf(Q * (1.f / 32768.f) - mean * mean, 0.f);
  const float rinv = 1.f / sqrtf(var + 1e-5f);
  const float a = g * rinv;
  return make_float2(a, bt - mean * a);
}

// ---------------- batched NT GEMM, MX fp8, 128x128 tile, BK=128 ------------------
// (round-14 proven config.)  EPI: 0 = fp8 (kv ints); 1 = attn spike {0,0x38};
// 2 = fp8 pre-act; 3 = +bias[row] then fp8 pre-act.
template <int EPI>
__global__ __launch_bounds__(256) void gemm8(const uchar* __restrict__ A,
                                             const uchar* __restrict__ B,
                                             uchar* __restrict__ Cout,
                                             const float* __restrict__ bias,
                                             int M, int N, int K,
                                             long sA, long sB, long sC) {
  __shared__ __align__(16) uchar lds[32768];  // A [0,16384), B [16384,32768)
  const int b = blockIdx.z;
  const uchar* Ab = A + (size_t)b * sA;
  const uchar* Bb = B + (size_t)b * sB;
  const int m0 = blockIdx.y * 128, n0 = blockIdx.x * 128;
  const int tid = threadIdx.x;
  const int wave = tid >> 6, lane = tid & 63;
  const int lrow = lane & 15, lquad = lane >> 4;
  const int wr = wave >> 1, wc = wave & 1;

  v4f acc[4][4];
#pragma unroll
  for (int i = 0; i < 4; i++)
#pragma unroll
    for (int j = 0; j < 4; j++) acc[i][j] = (v4f)0.f;

  const uchar* gA0 = Ab + (size_t)(m0 + 32 * wave + lrow) * K + lquad * 32;
  const uchar* gA1 = gA0 + (size_t)16 * K;
  const uchar* gB0 = Bb + (size_t)(n0 + 32 * wave + lrow) * K + lquad * 32;
  const uchar* gB1 = gB0 + (size_t)16 * K;
  uchar* lA0 = lds + (2 * wave) * 2048;
  uchar* lA1 = lA0 + 2048;
  uchar* lB0 = lds + 16384 + (2 * wave) * 2048;
  uchar* lB1 = lB0 + 2048;

  for (int k0 = 0; k0 < K; k0 += 128) {
    gload16(gA0, lA0);
    gload16(gA0 + 16, lA0 + 1024);
    gload16(gA1, lA1);
    gload16(gA1 + 16, lA1 + 1024);
    gload16(gB0, lB0);
    gload16(gB0 + 16, lB0 + 1024);
    gload16(gB1, lB1);
    gload16(gB1 + 16, lB1 + 1024);
    gA0 += 128; gA1 += 128; gB0 += 128; gB1 += 128;
    __syncthreads();
    const uchar* ra = lds + (size_t)(4 * wr) * 2048 + 16 * lane;
    const uchar* rb = lds + 16384 + (size_t)(4 * wc) * 2048 + 16 * lane;
    v8i af[4], bf[4];
#pragma unroll
    for (int i = 0; i < 4; i++) {
      const v4i lo = *(const v4i*)(ra + i * 2048);
      const v4i hi = *(const v4i*)(ra + i * 2048 + 1024);
      af[i][0] = lo[0]; af[i][1] = lo[1]; af[i][2] = lo[2]; af[i][3] = lo[3];
      af[i][4] = hi[0]; af[i][5] = hi[1]; af[i][6] = hi[2]; af[i][7] = hi[3];
    }
#pragma unroll
    for (int j = 0; j < 4; j++) {
      const v4i lo = *(const v4i*)(rb + j * 2048);
      const v4i hi = *(const v4i*)(rb + j * 2048 + 1024);
      bf[j][0] = lo[0]; bf[j][1] = lo[1]; bf[j][2] = lo[2]; bf[j][3] = lo[3];
      bf[j][4] = hi[0]; bf[j][5] = hi[1]; bf[j][6] = hi[2]; bf[j][7] = hi[3];
    }
#pragma unroll
    for (int i = 0; i < 4; i++)
#pragma unroll
      for (int j = 0; j < 4; j++)
        acc[i][j] = __builtin_amdgcn_mfma_scale_f32_16x16x128_f8f6f4(
            af[i], bf[j], acc[i][j], 0, 0, 0, 127, 0, 127);
    __syncthreads();
  }

  if (EPI == 3) {
#pragma unroll
    for (int mi = 0; mi < 4; mi++)
#pragma unroll
      for (int r = 0; r < 4; r++) {
        const float bi = bias[m0 + 64 * wr + 16 * mi + lquad * 4 + r];
#pragma unroll
        for (int ni = 0; ni < 4; ni++) acc[mi][ni][r] += bi;
      }
  }

  // Epilogue. C/D layout: col = lane&15, row = lquad*4 + reg.
#pragma unroll
  for (int mi = 0; mi < 4; mi++) {
    const int row0 = m0 + 64 * wr + 16 * mi + lquad * 4;
#pragma unroll
    for (int ni = 0; ni < 4; ni++) {
      const int col = n0 + 64 * wc + 16 * ni + lrow;
      uchar* cp = Cout + (size_t)b * sC + (size_t)row0 * N + col;
      if (EPI == 1) {
#pragma unroll
        for (int r = 0; r < 4; r++) {
          const float u = (acc[mi][ni][r] * 0.125f) / 1.1f - 0.5f;
          cp[(size_t)r * N] = (u >= 0.f) ? (uchar)0x38 : (uchar)0;
        }
      } else {
        const unsigned pk = pk4_fp8(acc[mi][ni][0], acc[mi][ni][1],
                                    acc[mi][ni][2], acc[mi][ni][3]);
#pragma unroll
        for (int r = 0; r < 4; r++) cp[(size_t)r * N] = (uchar)(pk >> (8 * r));
      }
    }
  }
}

// -------- BN partial stats from stored fp8: grid (8, nch) -------------------------
__global__ __launch_bounds__(256) void stats_part8_k(const uchar* __restrict__ in,
                                                     float* __restrict__ P,
                                                     long bstride) {
  const int part = blockIdx.x, c = blockIdx.y;
  const int tid = threadIdx.x;
  const int bi = part * 4 + (tid >> 6);
  const int lane = tid & 63;
  const uchar* p = in + (size_t)bi * bstride + (size_t)c * 1024 + lane * 16;
  const uint4 u = *(const uint4*)p;
  const int w4[4] = {(int)u.x, (int)u.y, (int)u.z, (int)u.w};
  float s = 0.f, s2 = 0.f;
#pragma unroll
  for (int t = 0; t < 4; t++) {
    const v2f a = dec2<false>(w4[t]);
    const v2f bb = dec2<true>(w4[t]);
    s += (a[0] + a[1]) + (bb[0] + bb[1]);
    s2 += a[0] * a[0] + a[1] * a[1] + bb[0] * bb[0] + bb[1] * bb[1];
  }
#pragma unroll
  for (int off = 32; off > 0; off >>= 1) {
    s += __shfl_down(s, off, 64);
    s2 += __shfl_down(s2, off, 64);
  }
  __shared__ float rs[4], rq[4];
  const int w = tid >> 6;
  if (lane == 0) { rs[w] = s; rq[w] = s2; }
  __syncthreads();
  if (tid == 0) {
    float2 o = make_float2(rs[0] + rs[1] + rs[2] + rs[3],
                           rq[0] + rq[1] + rq[2] + rq[3]);
    *(float2*)(P + (size_t)(c * 8 + part) * 2) = o;
  }
}

// -------- fused BN(finalize)+apply+spike: q (transpose) and k/v, one dispatch -----
// blocks [0,16384): qT tiles; [16384,32768): k/v linear (8192 each).
__global__ __launch_bounds__(256) void apply_all_k(const uchar* __restrict__ qkv8,
                                                   uchar* __restrict__ q8,
                                                   uchar* __restrict__ k8,
                                                   uchar* __restrict__ v8,
                                                   const float* __restrict__ P,
                                                   const float* __restrict__ qg, const float* __restrict__ qb,
                                                   const float* __restrict__ kg, const float* __restrict__ kb,
                                                   const float* __restrict__ vg, const float* __restrict__ vb) {
  const int bid = blockIdx.x;
  const int tid = threadIdx.x;
  if (bid < 16384) {
    // q: BN-apply + spike + transpose -> q8 [B,N,C]
    __shared__ uchar tile[32][33];
    const int nb = bid & 31, cb = (bid >> 5) & 15, b = bid >> 9;
    const int n0 = nb * 32, c0 = cb * 32;
    const uchar* in = qkv8 + (size_t)b * (1536 * 1024);
    const int cl = tid >> 3;            // 0..31
    const int n4 = (tid & 7) * 4;       // 0..28
    const int c = c0 + cl;
    const float2 ab = chan_affine(P, c, qg[c], qb[c]);
    const unsigned w = *(const unsigned*)(in + (size_t)c * 1024 + n0 + n4);
    const v2f a = dec2<false>((int)w);
    const v2f bb = dec2<true>((int)w);
    tile[cl][n4 + 0] = (ab.x * a[0] + ab.y >= 1.1f) ? (uchar)0x38 : (uchar)0;
    tile[cl][n4 + 1] = (ab.x * a[1] + ab.y >= 1.1f) ? (uchar)0x38 : (uchar)0;
    tile[cl][n4 + 2] = (ab.x * bb[0] + ab.y >= 1.1f) ? (uchar)0x38 : (uchar)0;
    tile[cl][n4 + 3] = (ab.x * bb[1] + ab.y >= 1.1f) ? (uchar)0x38 : (uchar)0;
    __syncthreads();
    uchar* out = q8 + (size_t)b * (NN * CC);
    const int nl = tid >> 3;
    const int cq = (tid & 7) * 4;
    uchar4 v;
    v.x = tile[cq][nl]; v.y = tile[cq + 1][nl];
    v.z = tile[cq + 2][nl]; v.w = tile[cq + 3][nl];
    *(uchar4*)(out + (size_t)(n0 + nl) * CC + c0 + cq) = v;
  } else {
    // k/v: BN-apply + spike in [B,C,N]
    const int t0 = bid - 16384;
    const int sec = t0 >> 13;           // 0:k, 1:v
    const int blk = t0 & 8191;
    const size_t t = (size_t)blk * 256 + tid;
    const size_t i = t * 8;
    const int b = (int)(i >> 19);
    const int rem = (int)(i & 524287);
    const int c = rem >> 10, n = rem & 1023;
    const int cg = 512 + 512 * sec + c;
    const float2 ab = chan_affine(P, cg, sec ? vg[c] : kg[c], sec ? vb[c] : kb[c]);
    const uchar* src = qkv8 + (size_t)b * (1536 * 1024) + (size_t)cg * 1024 + n;
    const uint2 u = *(const uint2*)src;
    ull packed = 0;
    {
      const v2f a = dec2<false>((int)u.x);
      const v2f bb = dec2<true>((int)u.x);
      const float f[4] = {a[0], a[1], bb[0], bb[1]};
#pragma unroll
      for (int j = 0; j < 4; j++)
        packed |= ((ab.x * f[j] + ab.y >= 1.1f) ? 0x38ull : 0ull) << (8 * j);
    }
    {
      const v2f a = dec2<false>((int)u.y);
      const v2f bb = dec2<true>((int)u.y);
      const float f[4] = {a[0], a[1], bb[0], bb[1]};
#pragma unroll
      for (int j = 0; j < 4; j++)
        packed |= ((ab.x * f[j] + ab.y >= 1.1f) ? 0x38ull : 0ull) << (8 * (4 + j));
    }
    uchar* dst = (sec ? v8 : k8) + (size_t)b * (CC * NN) + (size_t)c * 1024 + n;
    *(ull*)dst = packed;
  }
}

// -------- final BN(finalize)+apply+spike -> fp32 output ---------------------------
__global__ __launch_bounds__(256) void apply_final_k(const uchar* __restrict__ in,
                                                     float* __restrict__ outp,
                                                     const float* __restrict__ Pp,
                                                     const float* __restrict__ pg,
                                                     const float* __restrict__ pb) {
  const size_t idx = ((size_t)blockIdx.x * 256 + threadIdx.x) * 8;
  const int c = (int)((idx >> 10) & (CC - 1));
  const float2 ab = chan_affine(Pp, c, pg[c], pb[c]);
  const uint2 u = *(const uint2*)(in + idx);
  float of[8];
  {
    const v2f a = dec2<false>((int)u.x);
    const v2f bb = dec2<true>((int)u.x);
    of[0] = (ab.x * a[0] + ab.y >= 1.1f) ? 1.f : 0.f;
    of[1] = (ab.x * a[1] + ab.y >= 1.1f) ? 1.f : 0.f;
    of[2] = (ab.x * bb[0] + ab.y >= 1.1f) ? 1.f : 0.f;
    of[3] = (ab.x * bb[1] + ab.y >= 1.1f) ? 1.f : 0.f;
  }
  {
    const v2f a = dec2<false>((int)u.y);
    const v2f bb = dec2<true>((int)u.y);
    of[4] = (ab.x * a[0] + ab.y >= 1.1f) ? 1.f : 0.f;
    of[5] = (ab.x * a[1] + ab.y >= 1.1f) ? 1.f : 0.f;
    of[6] = (ab.x * bb[0] + ab.y >= 1.1f) ? 1.f : 0.f;
    of[7] = (ab.x * bb[1] + ab.y >= 1.1f) ? 1.f : 0.f;
  }
  float* op = outp + idx;
  *(float4*)op = make_float4(of[0], of[1], of[2], of[3]);
  *(float4*)(op + 4) = make_float4(of[4], of[5], of[6], of[7]);
}

// -------- fused prep: x transpose->fp8 [blocks 0,16384) + weight cvt [16384,17408)
__global__ __launch_bounds__(256) void prep_k(const float* __restrict__ x,
                                              const float* __restrict__ w0, const float* __restrict__ w1,
                                              const float* __restrict__ w2, const float* __restrict__ w3,
                                              uchar* __restrict__ xT8,
                                              uchar* __restrict__ o0, uchar* __restrict__ o1,
                                              uchar* __restrict__ o2, uchar* __restrict__ o3) {
  const int bid = blockIdx.x;
  const int tid = threadIdx.x;
  if (bid < 16384) {
    __shared__ uchar tile[32][33];
    const int nb = bid & 31, cb = (bid >> 5) & 15, b = bid >> 9;
    const int n0 = nb * 32, c0 = cb * 32;
    const float* in = x + (size_t)b * (CC * NN);
    const int tx = tid & 31, ty = tid >> 5;
#pragma unroll
    for (int i = 0; i < 32; i += 8) {
      tile[ty + i][tx] = enc1(in[(size_t)(c0 + ty + i) * NN + n0 + tx]);
    }
    __syncthreads();
    uchar* o = xT8 + (size_t)b * (NN * CC);
    const int nl = tid >> 3;
    const int cq = (tid & 7) * 4;
    uchar4 v;
    v.x = tile[cq][nl]; v.y = tile[cq + 1][nl];
    v.z = tile[cq + 2][nl]; v.w = tile[cq + 3][nl];
    *(uchar4*)(o + (size_t)(n0 + nl) * CC + c0 + cq) = v;
  } else {
    const int t = bid - 16384;      // [0,1024)
    const int mat = t >> 8, blk = t & 255;
    const float* src = (mat == 0) ? w0 : (mat == 1) ? w1 : (mat == 2) ? w2 : w3;
    uchar* dst = (mat == 0) ? o0 : (mat == 1) ? o1 : (mat == 2) ? o2 : o3;
    const int i = (blk * 256 + tid) * 4;
    float4 v = *(const float4*)(src + i);
    *(unsigned*)(dst + i) = pk4_fp8(v.x, v.y, v.z, v.w);
  }
}

extern "C" void kernel_launch(void* const* d_in, const int* in_sizes, int n_in,
                              void* d_out, int out_size, void* d_ws, size_t ws_size,
                              hipStream_t stream) {
  const float* x          = (const float*)d_in[0];
  const float* q_w        = (const float*)d_in[1];
  const float* q_gamma    = (const float*)d_in[2];
  const float* q_beta     = (const float*)d_in[3];
  const float* k_w        = (const float*)d_in[4];
  const float* k_gamma    = (const float*)d_in[5];
  const float* k_beta     = (const float*)d_in[6];
  const float* v_w        = (const float*)d_in[7];
  const float* v_gamma    = (const float*)d_in[8];
  const float* v_beta     = (const float*)d_in[9];
  const float* proj_w     = (const float*)d_in[10];
  const float* proj_gamma = (const float*)d_in[11];
  const float* proj_beta  = (const float*)d_in[12];
  const float* proj_b     = (const float*)d_in[13];

  char* base = (char*)d_ws;
  const size_t MB = 1u << 20;
  uchar*  xT8    = (uchar*)base;                // 16 MB [B,N,C] fp8
  uchar*  qkv8   = (uchar*)(base + 16 * MB);    // 48 MB [B,1536,1024] fp8 pre-acts
  uchar*  q8     = (uchar*)(base + 64 * MB);    // 16 MB [B,N,C] fp8 spikes
  uchar*  k8     = (uchar*)(base + 80 * MB);    // 16 MB [B,C,N]
  uchar*  v8     = (uchar*)(base + 96 * MB);    // 16 MB [B,C,N]
  uchar*  kvT8   = (uchar*)(base + 112 * MB);   //  8 MB [B,d,c]
  uchar*  attnT8 = (uchar*)(base + 120 * MB);   // 16 MB [B,N,d]
  uchar*  outpre8= (uchar*)(base + 136 * MB);   // 16 MB [B,C,N] fp8 proj pre-acts
  uchar*  wqkv8  = (uchar*)(base + 152 * MB);   // stacked q|k|v fp8
  uchar*  wp8    = wqkv8 + 3 * CC * CC;
  float*  P      = (float*)(base + 154 * MB);   // conv partials [1536][8][2]
  float*  Pp     = P + 1536 * 16;               // proj partials [512][8][2]
  float* dout = (float*)d_out;

  const long QKVL = (long)3 * CC * NN;   // fp8 bytes per batch
  const long NCL  = (long)NN * CC;
  const long CNL  = (long)CC * NN;
  const long KVL  = (long)CC * CC;

  // fused prep: x -> xT8 fp8 + weights -> fp8
  prep_k<<<17408, 256, 0, stream>>>(x, q_w, k_w, v_w, proj_w, xT8,
                                    wqkv8, wqkv8 + CC * CC, wqkv8 + 2 * CC * CC, wp8);

  // merged q/k/v conv -> fp8 pre-acts
  gemm8<2><<<dim3(NN / 128, 1536 / 128, BB), 256, 0, stream>>>(
      wqkv8, xT8, qkv8, nullptr, 1536, NN, CC, 0, NCL, QKVL);

  // BN stats from stored fp8
  stats_part8_k<<<dim3(8, 1536), 256, 0, stream>>>(qkv8, P, QKVL);

  // fused finalize+apply: q (transpose) + k + v spikes, one dispatch
  apply_all_k<<<32768, 256, 0, stream>>>(qkv8, q8, k8, v8, P,
                                         q_gamma, q_beta, k_gamma, k_beta,
                                         v_gamma, v_beta);

  // kvT8[d][c] = sum_n v[d][n] k[c][n]
  gemm8<0><<<dim3(CC / 128, CC / 128, BB), 256, 0, stream>>>(
      v8, k8, kvT8, nullptr, CC, CC, NN, CNL, CNL, KVL);
  // attnT8[n][d] = spike( sum_c q8[n][c]*kvT8[d][c] * 0.125, vth=0.5 )
  gemm8<1><<<dim3(CC / 128, NN / 128, BB), 256, 0, stream>>>(
      q8, kvT8, attnT8, nullptr, NN, CC, CC, NCL, KVL, NCL);
  // proj -> fp8 pre-acts (+bias)
  gemm8<3><<<dim3(NN / 128, CC / 128, BB), 256, 0, stream>>>(
      wp8, attnT8, outpre8, proj_b, CC, NN, CC, 0, NCL, CNL);

  // final BN stats + fused finalize+apply -> fp32 out
  stats_part8_k<<<dim3(8, CC), 256, 0, stream>>>(outpre8, Pp, CNL);
  apply_final_k<<<8192, 256, 0, stream>>>(outpre8, dout, Pp, proj_gamma, proj_beta);
}